// Round 1
// 358.117 us; speedup vs baseline: 1.0719x; 1.0719x over previous
//
#include <hip/hip_runtime.h>
#include <cmath>

#define H1    64
#define T1    50
#define T2    100
#define BATCH 8192
#define NB2   256        // sample-blocks of 32
#define NTILE 512        // global 16-sample tiles

typedef __attribute__((ext_vector_type(8))) short s16x8;
typedef __attribute__((ext_vector_type(4))) float f32x4;

#define MFMA16(a,b,c) __builtin_amdgcn_mfma_f32_16x16x32_bf16(a,b,c,0,0,0)

#define S_SIG  (-1.4426950408889634f)   // -1/ln2 : sigmoid gates (i,f,o)
#define S_TANH ( 2.8853900817779268f)   // +2/ln2 : tanh gate (g)

// ---- workspace byte offsets ----
#define OFF_FC1T  ((size_t)0)                                   // fp32 T1*BATCH
#define OFF_XF    ((size_t)1638400)                             // ushort T1*4*NTILE*64*8
#define OFF_WA1   ((size_t)(1638400 + 104857600))               // ushort 32768
#define OFF_WA2HH (OFF_WA1 + 65536)                             // ushort 32768
#define OFF_WA2IH (OFF_WA2HH + 65536)                           // ushort 65536
#define OFF_PART  (OFF_WA2IH + 131072)                          // fp32 2*T2*BATCH
#define OFF_BS    (OFF_PART + 6553600)                          // fp32 2*256 prescaled bias

__device__ __forceinline__ float rcp_(float x) { return __builtin_amdgcn_rcpf(x); }
__device__ __forceinline__ float exp2_(float x) {
#if __has_builtin(__builtin_amdgcn_exp2f)
    return __builtin_amdgcn_exp2f(x);
#else
    return exp2f(x);
#endif
}
__device__ __forceinline__ float sigp_(float e)  { return rcp_(1.f + exp2_(e)); }
__device__ __forceinline__ float tanhp_(float e) { return 1.f - 2.f * rcp_(1.f + exp2_(e)); }
__device__ __forceinline__ float tanhc_(float c) { return tanhp_(S_TANH * c); }
__device__ __forceinline__ float tanh_(float x)  { return tanhc_(x); }

__device__ __forceinline__ unsigned short bf16_rne(float x) {
    unsigned int u = __float_as_uint(x);
    u += 0x7fffu + ((u >> 16) & 1u);
    return (unsigned short)(u >> 16);
}

// packed f32x2 -> bf16x2 (RNE), gfx950 has the instruction but no builtin (T12)
__device__ __forceinline__ unsigned int cvtpk_bf16(float a, float b) {
    unsigned int r;
    asm("v_cvt_pk_bf16_f32 %0, %1, %2" : "=v"(r) : "v"(a), "v"(b));
    return r;
}

// barrier that drains ONLY LDS ops: global stores / prefetch loads / atomics
// stay in flight across the step boundary (the compiler's __syncthreads would
// emit s_waitcnt vmcnt(0) and put the L2 round-trip on the serial critical path)
__device__ __forceinline__ void bar_lgkm() {
    asm volatile("s_waitcnt lgkmcnt(0)\n\ts_barrier" ::: "memory");
}

// fused LSTM cell: 5 exp2 + 3 rcp (was 5+5).
//   sig(f)*c            = c / (1+Ef)
//   sig(i)*tanh(g)      = (Eg-1) / ((1+Ei)(1+Eg))
//   sig(o)*tanh(c_new)  = (Ec-1) / ((1+Eo)(1+Ec))
// Eg/Ec clamped at 2^100 so the fused form can't hit inf*0 = NaN.
#define CELL_PACK(ACC)                                                         \
        float hv[4];                                                           \
        _Pragma("unroll")                                                      \
        for (int r = 0; r < 4; ++r) {                                          \
            float Ei = exp2_(ACC[0][r]);                                       \
            float Ef = exp2_(ACC[1][r]);                                       \
            float Eg = exp2_(fminf(ACC[2][r], 100.f));                         \
            float Eo = exp2_(ACC[3][r]);                                       \
            float rf  = rcp_(1.f + Ef);                                        \
            float rig = rcp_((1.f + Ei) * (1.f + Eg));                         \
            float cc  = c4[r] * rf + (Eg - 1.f) * rig;                         \
            c4[r] = cc;                                                        \
            float Ec  = exp2_(fminf(S_TANH * cc, 100.f));                      \
            float roc = rcp_((1.f + Eo) * (1.f + Ec));                         \
            hv[r] = (Ec - 1.f) * roc;                                          \
        }                                                                      \
        uint2 vhi, vlo;                                                        \
        vhi.x = cvtpk_bf16(hv[0], hv[1]);                                      \
        vhi.y = cvtpk_bf16(hv[2], hv[3]);                                      \
        {                                                                      \
            float q0 = hv[0] - __uint_as_float(vhi.x << 16);                   \
            float q1 = hv[1] - __uint_as_float(vhi.x & 0xffff0000u);           \
            float q2 = hv[2] - __uint_as_float(vhi.y << 16);                   \
            float q3 = hv[3] - __uint_as_float(vhi.y & 0xffff0000u);           \
            vlo.x = cvtpk_bf16(q0, q1);                                        \
            vlo.y = cvtpk_bf16(q2, q3);                                        \
        }

// ---------------- k_pre: weight frags (prescaled) + prescaled bias + fc1 + zero(part) ----------------
__global__ __launch_bounds__(256) void k_pre(
    const float* __restrict__ whh1f, const float* __restrict__ whh1b,
    const float* __restrict__ whh2f, const float* __restrict__ whh2b,
    const float* __restrict__ wih2f, const float* __restrict__ wih2b,
    const float* __restrict__ b2f,   const float* __restrict__ b2b,
    const float* __restrict__ x, const float* __restrict__ fc1w,
    const float* __restrict__ fc1b,
    unsigned short* __restrict__ WA1, unsigned short* __restrict__ WA2HH,
    unsigned short* __restrict__ WA2IH, float* __restrict__ fc1T,
    float* __restrict__ part, float* __restrict__ BS)
{
    __shared__ float wls[1000];
    __shared__ float bls[50];
    int tid = threadIdx.x;
    int blk = blockIdx.x;
    if (blk < 64) {
        int i = blk * 256 + tid;                    // 16384 slots
        if (i < 8192) {
            int a   = i >> 12;                      // 0: layer1 whh, 1: layer2 whh
            int r   = i & 4095;
            int dir = r >> 11, rem = r & 2047;
            int mt  = rem >> 7, rem2 = rem & 127;
            int kk  = rem2 >> 6, l = rem2 & 63;
            const float* s_ = a ? (dir ? whh2b : whh2f) : (dir ? whh1b : whh1f);
            unsigned short* d_ = a ? WA2HH : WA1;
            int gate = mt * 16 + (l & 15);
            float sc = ((gate >> 6) == 2) ? S_TANH : S_SIG;
            int k0   = kk * 32 + (l >> 4) * 8;
            const float* p = s_ + gate * 64 + k0;
            unsigned short* q = d_ + (size_t)r * 8;
#pragma unroll
            for (int j = 0; j < 8; ++j) q[j] = bf16_rne(p[j] * sc);
        } else {
            int r   = i - 8192;                     // layer2 wih, 8192 slots
            int dir = r >> 12, rem = r & 4095;
            int mt  = rem >> 8, rem2 = rem & 255;
            int kk  = rem2 >> 6, l = rem2 & 63;
            const float* s_ = dir ? wih2b : wih2f;
            int gate = mt * 16 + (l & 15);
            float sc = ((gate >> 6) == 2) ? S_TANH : S_SIG;
            int k0   = kk * 32 + (l >> 4) * 8;
            const float* p = s_ + gate * 128 + k0;
            unsigned short* q = WA2IH + (size_t)r * 8;
#pragma unroll
            for (int j = 0; j < 8; ++j) q[j] = bf16_rne(p[j] * sc);
        }
    } else if (blk < 96) {
        // fc1
        for (int i = tid; i < 1000; i += 256) wls[i] = fc1w[i];
        if (tid < 50) bls[tid] = fc1b[tid];
        __syncthreads();
        int bidx = (blk - 64) * 256 + tid;
        float xv[20];
#pragma unroll
        for (int i = 0; i < 20; ++i) xv[i] = x[bidx * 20 + i];
        for (int t = 0; t < T1; ++t) {
            float s = bls[t];
#pragma unroll
            for (int i = 0; i < 20; ++i) s += xv[i] * wls[t * 20 + i];
            fc1T[t * BATCH + bidx] = s;
        }
    } else if (blk < 352) {
        // zero the fc2 partial accumulator (atomicAdd target)
        const int n = 2 * T2 * BATCH;
        for (int i = (blk - 96) * 256 + tid; i < n; i += 256 * 256) part[i] = 0.f;
    } else {
        // prescaled layer-2 bias table: BS[dir*256 + m] = bias[m] * sc(m>>6)
        for (int i = tid; i < 512; i += 256) {
            int d = i >> 8, m = i & 255;
            const float* bb = d ? b2b : b2f;
            float sc = ((m >> 6) == 2) ? S_TANH : S_SIG;
            BS[i] = bb[m] * sc;
        }
    }
}

// ---------------- layer-1 BiLSTM ----------------
// Changes vs R3: lgkm-only barrier (XF global store no longer drained per step),
// 2-step unroll w/ static dbuf index, Htf[0] zero-init (uniform step-0 path),
// cvt_pk packing, 3-rcp fused cell.
__global__ __launch_bounds__(512, 4) void k_lstm1(
    const float* __restrict__ wih1f, const float* __restrict__ b1f,
    const float* __restrict__ wih1b, const float* __restrict__ b1b,
    const unsigned short* __restrict__ WA1,
    const float* __restrict__ fc1T,
    unsigned short* __restrict__ XF)
{
    __shared__ float x1s[T1][32];
    __shared__ unsigned short Htf[2][2][2][2][64][8];   // [buf][half][kk][wsh][l][j]
    int tid  = threadIdx.x;
    int lane = tid & 63;
    int w    = __builtin_amdgcn_readfirstlane(tid >> 6);
    int wh   = w & 3, wsh = w >> 2;
    int quad = lane >> 4, col = lane & 15;
    int dir  = blockIdx.y, bblk = blockIdx.x;

    for (int i = tid; i < T1 * 32; i += 512) {
        int t = i >> 5, s = i & 31;
        x1s[t][s] = fc1T[t * BATCH + bblk * 32 + s];
    }
    {   // zero Htf[0] (8192 B) so step 0 can run the uniform MFMA path (h_prev = 0)
        uint4* z = (uint4*)&Htf[0][0][0][0][0][0];
        uint4 zz; zz.x = 0u; zz.y = 0u; zz.z = 0u; zz.w = 0u;
        z[tid] = zz;
    }
    const float* wih = dir ? wih1b : wih1f;
    const float* bia = dir ? b1b : b1f;
    f32x4 wvv[4], bvv[4];
#pragma unroll
    for (int g = 0; g < 4; ++g) {
        float sc = (g == 2) ? S_TANH : S_SIG;
#pragma unroll
        for (int r = 0; r < 4; ++r) {
            int gate = g * 64 + wh * 16 + quad * 4 + r;
            wvv[g][r] = wih[gate] * sc;
            bvv[g][r] = bia[gate] * sc;
        }
    }
    s16x8 whhA[4][2];
#pragma unroll
    for (int g = 0; g < 4; ++g)
#pragma unroll
        for (int kk = 0; kk < 2; ++kk)
            whhA[g][kk] = *(const s16x8*)(WA1 +
                ((size_t)((dir * 16 + (g * 4 + wh)) * 2 + kk) * 64 + lane) * 8);

    float c4[4];
#pragma unroll
    for (int r = 0; r < 4; ++r) c4[r] = 0.f;

    int lq  = 2 * (wh & 1) + (quad >> 1);
    int lp  = lq * 16 + col;
    int jo  = (quad & 1) * 4;
    int kkw = wh >> 1;
    int kk1 = dir * 2 + kkw;
    int gtile = bblk * 2 + wsh;
    __syncthreads();

    int t = dir ? (T1 - 1) : 0;
    const int dt = dir ? -1 : 1;

#define L1_STEP(RB, WB)                                                        \
    {                                                                          \
        float xt = x1s[t][wsh * 16 + col];                                     \
        f32x4 acc[4];                                                          \
        _Pragma("unroll") for (int g = 0; g < 4; ++g)                          \
            _Pragma("unroll") for (int r = 0; r < 4; ++r)                      \
                acc[g][r] = bvv[g][r] + wvv[g][r] * xt;                        \
        {                                                                      \
            s16x8 hb00 = *(const s16x8*)&Htf[RB][0][0][wsh][lane][0];          \
            s16x8 hb01 = *(const s16x8*)&Htf[RB][0][1][wsh][lane][0];          \
            s16x8 hb10 = *(const s16x8*)&Htf[RB][1][0][wsh][lane][0];          \
            s16x8 hb11 = *(const s16x8*)&Htf[RB][1][1][wsh][lane][0];          \
            _Pragma("unroll") for (int g = 0; g < 4; ++g) {                    \
                f32x4 a = MFMA16(whhA[g][0], hb00, acc[g]);                    \
                a = MFMA16(whhA[g][1], hb01, a);                               \
                a = MFMA16(whhA[g][0], hb10, a);                               \
                a = MFMA16(whhA[g][1], hb11, a);                               \
                acc[g] = a;                                                    \
            }                                                                  \
        }                                                                      \
        CELL_PACK(acc)                                                         \
        *(uint2*)&Htf[WB][0][kkw][wsh][lp][jo] = vhi;                          \
        *(uint2*)&Htf[WB][1][kkw][wsh][lp][jo] = vlo;                          \
        *(uint2*)(XF + ((((size_t)t * 4 + kk1) * NTILE + gtile) * 64 + lp) * 8 + jo) = vhi; \
        bar_lgkm();                                                            \
        t += dt;                                                               \
    }

    for (int it = 0; it < T1 / 2; ++it) {
        L1_STEP(0, 1)
        L1_STEP(1, 0)
    }
#undef L1_STEP
}

// ---------------- layer-2 BiLSTM ----------------
// Changes vs R3: lgkm-only barrier (atomicAdd + XF prefetch no longer drained
// per step), 4-step unroll w/ static dbuf + static xb buffers (no register
// copies), Htf[0] zero-init, hoisted BS bias loads, cvt_pk packing, fused cell.
__global__ __launch_bounds__(512, 4) void k_lstm2(
    const float* __restrict__ BS,
    const float* __restrict__ fc2w,
    const unsigned short* __restrict__ WA2HH,
    const unsigned short* __restrict__ WA2IH,
    const unsigned short* __restrict__ XF,
    float* __restrict__ part)
{
    __shared__ unsigned short wAl[16][4][64][8];        // 64 KB: dir slice of WA2IH
    __shared__ unsigned short Htf[2][2][2][2][64][8];   // 16 KB
    int tid  = threadIdx.x;
    int lane = tid & 63;
    int w    = __builtin_amdgcn_readfirstlane(tid >> 6);
    int wh   = w & 3, wsh = w >> 2;
    int quad = lane >> 4, col = lane & 15;
    int dir  = blockIdx.y, bblk = blockIdx.x;
    int gtile = bblk * 2 + wsh;

    {   // stage Wih A-fragments (our dir) into LDS
        const uint4* src = (const uint4*)(WA2IH + (size_t)dir * 32768);
        uint4* dst = (uint4*)&wAl[0][0][0][0];
        for (int i = tid; i < 4096; i += 512) dst[i] = src[i];
    }
    {   // zero Htf[0] (8192 B)
        uint4* z = (uint4*)&Htf[0][0][0][0][0][0];
        uint4 zz; zz.x = 0u; zz.y = 0u; zz.z = 0u; zz.w = 0u;
        z[tid] = zz;
    }
    float f2v[4];
#pragma unroll
    for (int r = 0; r < 4; ++r)
        f2v[r] = fc2w[dir * 64 + wh * 16 + quad * 4 + r];

    s16x8 whhA[4][2];
#pragma unroll
    for (int g = 0; g < 4; ++g)
#pragma unroll
        for (int kk = 0; kk < 2; ++kk)
            whhA[g][kk] = *(const s16x8*)(WA2HH +
                ((size_t)((dir * 16 + (g * 4 + wh)) * 2 + kk) * 64 + lane) * 8);

    // hoist prescaled bias (was 4 global float4 loads per even step)
    float4 bvv4[4];
    {
        const float* bsrc = BS + dir * 256 + wh * 16 + quad * 4;
#pragma unroll
        for (int g = 0; g < 4; ++g)
            bvv4[g] = *(const float4*)(bsrc + g * 64);
    }

    float c4[4];
#pragma unroll
    for (int r = 0; r < 4; ++r) c4[r] = 0.f;

    int lq  = 2 * (wh & 1) + (quad >> 1);
    int lp  = lq * 16 + col;
    int jo  = (quad & 1) * 4;
    int kkw = wh >> 1;

    // preload pair-0 X-frags
    s16x8 xbA[4], xbB[4];
    {
        int tp0 = dir ? (T1 - 1) : 0;
#pragma unroll
        for (int kk = 0; kk < 4; ++kk)
            xbA[kk] = *(const s16x8*)(XF +
                (((size_t)(tp0 * 4 + kk) * NTILE + gtile) * 64 + lane) * 8);
    }
    f32x4 xacc[4];
    __syncthreads();

    int t2 = dir ? (T2 - 1) : 0;
    const int dt = dir ? -1 : 1;
    int tpn = dir ? (T1 - 2) : 1;       // next pair to prefetch

#define L2_HIDCELL(RB, WB)                                                     \
    {                                                                          \
        s16x8 hb00 = *(const s16x8*)&Htf[RB][0][0][wsh][lane][0];              \
        s16x8 hb01 = *(const s16x8*)&Htf[RB][0][1][wsh][lane][0];              \
        s16x8 hb10 = *(const s16x8*)&Htf[RB][1][0][wsh][lane][0];              \
        s16x8 hb11 = *(const s16x8*)&Htf[RB][1][1][wsh][lane][0];              \
        f32x4 acc[4];                                                          \
        _Pragma("unroll") for (int g = 0; g < 4; ++g) {                        \
            f32x4 a = MFMA16(whhA[g][0], hb00, xacc[g]);                       \
            a = MFMA16(whhA[g][1], hb01, a);                                   \
            a = MFMA16(whhA[g][0], hb10, a);                                   \
            a = MFMA16(whhA[g][1], hb11, a);                                   \
            acc[g] = a;                                                        \
        }                                                                      \
        CELL_PACK(acc)                                                         \
        *(uint2*)&Htf[WB][0][kkw][wsh][lp][jo] = vhi;                          \
        *(uint2*)&Htf[WB][1][kkw][wsh][lp][jo] = vlo;                          \
        float pacc = f2v[0]*hv[0] + f2v[1]*hv[1] + f2v[2]*hv[2] + f2v[3]*hv[3];\
        pacc += __shfl_xor(pacc, 16);                                          \
        pacc += __shfl_xor(pacc, 32);                                          \
        if (lane < 16)                                                         \
            atomicAdd(&part[((size_t)(dir * T2 + t2)) * BATCH + bblk * 32 + wsh * 16 + lane], pacc); \
        bar_lgkm();                                                            \
        t2 += dt;                                                              \
    }

#define L2_EVEN(XBU, XBP, RB, WB)                                              \
    {                                                                          \
        _Pragma("unroll") for (int g = 0; g < 4; ++g) {                        \
            f32x4 a;                                                           \
            a[0] = bvv4[g].x; a[1] = bvv4[g].y;                                \
            a[2] = bvv4[g].z; a[3] = bvv4[g].w;                                \
            _Pragma("unroll") for (int kk = 0; kk < 4; ++kk) {                 \
                s16x8 wa = *(const s16x8*)&wAl[g * 4 + wh][kk][lane][0];       \
                a = MFMA16(wa, XBU[kk], a);                                    \
            }                                                                  \
            xacc[g] = a;                                                       \
        }                                                                      \
        _Pragma("unroll") for (int kk = 0; kk < 4; ++kk)                       \
            XBP[kk] = *(const s16x8*)(XF +                                     \
                (((size_t)(tpn * 4 + kk) * NTILE + gtile) * 64 + lane) * 8);   \
        tpn += dt;                                                             \
        if (tpn < 0) tpn = 0;                                                  \
        if (tpn > T1 - 1) tpn = T1 - 1;                                        \
    }                                                                          \
    L2_HIDCELL(RB, WB)

    for (int it = 0; it < T2 / 4; ++it) {
        L2_EVEN(xbA, xbB, 0, 1)
        L2_HIDCELL(1, 0)
        L2_EVEN(xbB, xbA, 0, 1)
        L2_HIDCELL(1, 0)
    }
#undef L2_EVEN
#undef L2_HIDCELL
}

// ---------------- combine + tanh ----------------
__global__ __launch_bounds__(256) void k_fc2(const float* __restrict__ part,
                                             const float* __restrict__ fc2b,
                                             float* __restrict__ out) {
    int u = blockIdx.x * 256 + threadIdx.x;
    if (u >= BATCH * T2) return;
    int b = u / T2, t = u - b * T2;
    float p = part[(size_t)t * BATCH + b] + part[((size_t)T2 + t) * BATCH + b] + fc2b[0];
    out[u] = tanh_(p);
}

extern "C" void kernel_launch(void* const* d_in, const int* in_sizes, int n_in,
                              void* d_out, int out_size, void* d_ws, size_t ws_size,
                              hipStream_t stream) {
    const float* x      = (const float*)d_in[0];
    const float* fc1w   = (const float*)d_in[1];
    const float* fc1b   = (const float*)d_in[2];
    const float* r1wihf = (const float*)d_in[3];
    const float* r1whhf = (const float*)d_in[4];
    const float* r1bf   = (const float*)d_in[5];
    const float* r1wihb = (const float*)d_in[6];
    const float* r1whhb = (const float*)d_in[7];
    const float* r1bb   = (const float*)d_in[8];
    const float* r2wihf = (const float*)d_in[9];
    const float* r2whhf = (const float*)d_in[10];
    const float* r2bf   = (const float*)d_in[11];
    const float* r2wihb = (const float*)d_in[12];
    const float* r2whhb = (const float*)d_in[13];
    const float* r2bb   = (const float*)d_in[14];
    const float* fc2w   = (const float*)d_in[15];
    const float* fc2b   = (const float*)d_in[16];
    char* ws   = (char*)d_ws;
    float* out = (float*)d_out;

    float*          fc1T  = (float*)(ws + OFF_FC1T);
    unsigned short* XF    = (unsigned short*)(ws + OFF_XF);
    unsigned short* WA1   = (unsigned short*)(ws + OFF_WA1);
    unsigned short* WA2HH = (unsigned short*)(ws + OFF_WA2HH);
    unsigned short* WA2IH = (unsigned short*)(ws + OFF_WA2IH);
    float*          partp = (float*)(ws + OFF_PART);
    float*          BS    = (float*)(ws + OFF_BS);

    k_pre<<<353, 256, 0, stream>>>(r1whhf, r1whhb, r2whhf, r2whhb, r2wihf, r2wihb,
                                   r2bf, r2bb, x, fc1w, fc1b,
                                   WA1, WA2HH, WA2IH, fc1T, partp, BS);
    dim3 g1(NB2, 2);
    k_lstm1<<<g1, 512, 0, stream>>>(r1wihf, r1bf, r1wihb, r1bb, WA1, fc1T, XF);
    k_lstm2<<<g1, 512, 0, stream>>>(BS, fc2w, WA2HH, WA2IH, XF, partp);
    k_fc2<<<(BATCH * T2 + 255) / 256, 256, 0, stream>>>(partp, fc2b, out);
}

// Round 2
// 354.005 us; speedup vs baseline: 1.0844x; 1.0116x over previous
//
#include <hip/hip_runtime.h>
#include <cmath>

#define H1    64
#define T1    50
#define T2    100
#define BATCH 8192
#define NB2   256        // sample-blocks of 32
#define NTILE 512        // global 16-sample tiles

typedef __attribute__((ext_vector_type(8))) short s16x8;
typedef __attribute__((ext_vector_type(4))) float f32x4;

#define MFMA16(a,b,c) __builtin_amdgcn_mfma_f32_16x16x32_bf16(a,b,c,0,0,0)

#define S_SIG  (-1.4426950408889634f)   // -1/ln2 : sigmoid gates (i,f,o)
#define S_TANH ( 2.8853900817779268f)   // +2/ln2 : tanh gate (g)

// ---- workspace byte offsets ----
#define OFF_FC1T  ((size_t)0)                                   // fp32 T1*BATCH
#define OFF_XF    ((size_t)1638400)                             // ushort T1*4*NTILE*64*8
#define OFF_WA1   ((size_t)(1638400 + 104857600))               // ushort 32768
#define OFF_WA2HH (OFF_WA1 + 65536)                             // ushort 32768
#define OFF_WA2IH (OFF_WA2HH + 65536)                           // ushort 65536
#define OFF_PART  (OFF_WA2IH + 131072)                          // fp32 2*T2*BATCH
#define OFF_BS    (OFF_PART + 6553600)                          // fp32 2*256 prescaled bias

__device__ __forceinline__ float rcp_(float x) { return __builtin_amdgcn_rcpf(x); }
__device__ __forceinline__ float exp2_(float x) {
#if __has_builtin(__builtin_amdgcn_exp2f)
    return __builtin_amdgcn_exp2f(x);
#else
    return exp2f(x);
#endif
}
__device__ __forceinline__ float sigp_(float e)  { return rcp_(1.f + exp2_(e)); }
__device__ __forceinline__ float tanhp_(float e) { return 1.f - 2.f * rcp_(1.f + exp2_(e)); }
__device__ __forceinline__ float tanhc_(float c) { return tanhp_(S_TANH * c); }
__device__ __forceinline__ float tanh_(float x)  { return tanhc_(x); }

__device__ __forceinline__ unsigned short bf16_rne(float x) {
    unsigned int u = __float_as_uint(x);
    u += 0x7fffu + ((u >> 16) & 1u);
    return (unsigned short)(u >> 16);
}

// packed f32x2 -> bf16x2 (RNE), gfx950 has the instruction but no builtin (T12)
__device__ __forceinline__ unsigned int cvtpk_bf16(float a, float b) {
    unsigned int r;
    asm("v_cvt_pk_bf16_f32 %0, %1, %2" : "=v"(r) : "v"(a), "v"(b));
    return r;
}

// barrier that drains ONLY LDS ops: global stores / prefetch loads / atomics
// stay in flight across the step boundary (the compiler's __syncthreads would
// emit s_waitcnt vmcnt(0) and put the L2 round-trip on the serial critical path)
__device__ __forceinline__ void bar_lgkm() {
    asm volatile("s_waitcnt lgkmcnt(0)\n\ts_barrier" ::: "memory");
}

// fused LSTM cell: 5 exp2 + 3 rcp.
//   sig(f)*c            = c / (1+Ef)
//   sig(i)*tanh(g)      = (Eg-1) / ((1+Ei)(1+Eg))
//   sig(o)*tanh(c_new)  = (Ec-1) / ((1+Eo)(1+Ec))
// Eg/Ec clamped at 2^100 so the fused form can't hit inf*0 = NaN.
#define CELL_PACK(ACC)                                                         \
        float hv[4];                                                           \
        _Pragma("unroll")                                                      \
        for (int r = 0; r < 4; ++r) {                                          \
            float Ei = exp2_(ACC[0][r]);                                       \
            float Ef = exp2_(ACC[1][r]);                                       \
            float Eg = exp2_(fminf(ACC[2][r], 100.f));                         \
            float Eo = exp2_(ACC[3][r]);                                       \
            float rf  = rcp_(1.f + Ef);                                        \
            float rig = rcp_((1.f + Ei) * (1.f + Eg));                         \
            float cc  = c4[r] * rf + (Eg - 1.f) * rig;                         \
            c4[r] = cc;                                                        \
            float Ec  = exp2_(fminf(S_TANH * cc, 100.f));                      \
            float roc = rcp_((1.f + Eo) * (1.f + Ec));                         \
            hv[r] = (Ec - 1.f) * roc;                                          \
        }                                                                      \
        uint2 vhi, vlo;                                                        \
        vhi.x = cvtpk_bf16(hv[0], hv[1]);                                      \
        vhi.y = cvtpk_bf16(hv[2], hv[3]);                                      \
        {                                                                      \
            float q0 = hv[0] - __uint_as_float(vhi.x << 16);                   \
            float q1 = hv[1] - __uint_as_float(vhi.x & 0xffff0000u);           \
            float q2 = hv[2] - __uint_as_float(vhi.y << 16);                   \
            float q3 = hv[3] - __uint_as_float(vhi.y & 0xffff0000u);           \
            vlo.x = cvtpk_bf16(q0, q1);                                        \
            vlo.y = cvtpk_bf16(q2, q3);                                        \
        }

// ---------------- k_pre: weight frags (prescaled) + prescaled bias + fc1 + zero(part) ----------------
__global__ __launch_bounds__(256) void k_pre(
    const float* __restrict__ whh1f, const float* __restrict__ whh1b,
    const float* __restrict__ whh2f, const float* __restrict__ whh2b,
    const float* __restrict__ wih2f, const float* __restrict__ wih2b,
    const float* __restrict__ b2f,   const float* __restrict__ b2b,
    const float* __restrict__ x, const float* __restrict__ fc1w,
    const float* __restrict__ fc1b,
    unsigned short* __restrict__ WA1, unsigned short* __restrict__ WA2HH,
    unsigned short* __restrict__ WA2IH, float* __restrict__ fc1T,
    float* __restrict__ part, float* __restrict__ BS)
{
    __shared__ float wls[1000];
    __shared__ float bls[50];
    int tid = threadIdx.x;
    int blk = blockIdx.x;
    if (blk < 64) {
        int i = blk * 256 + tid;                    // 16384 slots
        if (i < 8192) {
            int a   = i >> 12;                      // 0: layer1 whh, 1: layer2 whh
            int r   = i & 4095;
            int dir = r >> 11, rem = r & 2047;
            int mt  = rem >> 7, rem2 = rem & 127;
            int kk  = rem2 >> 6, l = rem2 & 63;
            const float* s_ = a ? (dir ? whh2b : whh2f) : (dir ? whh1b : whh1f);
            unsigned short* d_ = a ? WA2HH : WA1;
            int gate = mt * 16 + (l & 15);
            float sc = ((gate >> 6) == 2) ? S_TANH : S_SIG;
            int k0   = kk * 32 + (l >> 4) * 8;
            const float* p = s_ + gate * 64 + k0;
            unsigned short* q = d_ + (size_t)r * 8;
#pragma unroll
            for (int j = 0; j < 8; ++j) q[j] = bf16_rne(p[j] * sc);
        } else {
            int r   = i - 8192;                     // layer2 wih, 8192 slots
            int dir = r >> 12, rem = r & 4095;
            int mt  = rem >> 8, rem2 = rem & 255;
            int kk  = rem2 >> 6, l = rem2 & 63;
            const float* s_ = dir ? wih2b : wih2f;
            int gate = mt * 16 + (l & 15);
            float sc = ((gate >> 6) == 2) ? S_TANH : S_SIG;
            int k0   = kk * 32 + (l >> 4) * 8;
            const float* p = s_ + gate * 128 + k0;
            unsigned short* q = WA2IH + (size_t)r * 8;
#pragma unroll
            for (int j = 0; j < 8; ++j) q[j] = bf16_rne(p[j] * sc);
        }
    } else if (blk < 96) {
        // fc1
        for (int i = tid; i < 1000; i += 256) wls[i] = fc1w[i];
        if (tid < 50) bls[tid] = fc1b[tid];
        __syncthreads();
        int bidx = (blk - 64) * 256 + tid;
        float xv[20];
#pragma unroll
        for (int i = 0; i < 20; ++i) xv[i] = x[bidx * 20 + i];
        for (int t = 0; t < T1; ++t) {
            float s = bls[t];
#pragma unroll
            for (int i = 0; i < 20; ++i) s += xv[i] * wls[t * 20 + i];
            fc1T[t * BATCH + bidx] = s;
        }
    } else if (blk < 352) {
        // zero the fc2 partial accumulator (atomicAdd target)
        const int n = 2 * T2 * BATCH;
        for (int i = (blk - 96) * 256 + tid; i < n; i += 256 * 256) part[i] = 0.f;
    } else {
        // prescaled layer-2 bias table: BS[dir*256 + m] = bias[m] * sc(m>>6)
        for (int i = tid; i < 512; i += 256) {
            int d = i >> 8, m = i & 255;
            const float* bb = d ? b2b : b2f;
            float sc = ((m >> 6) == 2) ? S_TANH : S_SIG;
            BS[i] = bb[m] * sc;
        }
    }
}

// ---------------- layer-1 BiLSTM ----------------
// R2 changes: setprio around MFMA cluster, running XF store pointer.
__global__ __launch_bounds__(512, 4) void k_lstm1(
    const float* __restrict__ wih1f, const float* __restrict__ b1f,
    const float* __restrict__ wih1b, const float* __restrict__ b1b,
    const unsigned short* __restrict__ WA1,
    const float* __restrict__ fc1T,
    unsigned short* __restrict__ XF)
{
    __shared__ float x1s[T1][32];
    __shared__ unsigned short Htf[2][2][2][2][64][8];   // [buf][half][kk][wsh][l][j]
    int tid  = threadIdx.x;
    int lane = tid & 63;
    int w    = __builtin_amdgcn_readfirstlane(tid >> 6);
    int wh   = w & 3, wsh = w >> 2;
    int quad = lane >> 4, col = lane & 15;
    int dir  = blockIdx.y, bblk = blockIdx.x;

    for (int i = tid; i < T1 * 32; i += 512) {
        int t = i >> 5, s = i & 31;
        x1s[t][s] = fc1T[t * BATCH + bblk * 32 + s];
    }
    {   // zero Htf[0] (8192 B) so step 0 can run the uniform MFMA path (h_prev = 0)
        uint4* z = (uint4*)&Htf[0][0][0][0][0][0];
        uint4 zz; zz.x = 0u; zz.y = 0u; zz.z = 0u; zz.w = 0u;
        z[tid] = zz;
    }
    const float* wih = dir ? wih1b : wih1f;
    const float* bia = dir ? b1b : b1f;
    f32x4 wvv[4], bvv[4];
#pragma unroll
    for (int g = 0; g < 4; ++g) {
        float sc = (g == 2) ? S_TANH : S_SIG;
#pragma unroll
        for (int r = 0; r < 4; ++r) {
            int gate = g * 64 + wh * 16 + quad * 4 + r;
            wvv[g][r] = wih[gate] * sc;
            bvv[g][r] = bia[gate] * sc;
        }
    }
    s16x8 whhA[4][2];
#pragma unroll
    for (int g = 0; g < 4; ++g)
#pragma unroll
        for (int kk = 0; kk < 2; ++kk)
            whhA[g][kk] = *(const s16x8*)(WA1 +
                ((size_t)((dir * 16 + (g * 4 + wh)) * 2 + kk) * 64 + lane) * 8);

    float c4[4];
#pragma unroll
    for (int r = 0; r < 4; ++r) c4[r] = 0.f;

    int lq  = 2 * (wh & 1) + (quad >> 1);
    int lp  = lq * 16 + col;
    int jo  = (quad & 1) * 4;
    int kkw = wh >> 1;
    int kk1 = dir * 2 + kkw;
    int gtile = bblk * 2 + wsh;
    __syncthreads();

    int t = dir ? (T1 - 1) : 0;
    const int dt = dir ? -1 : 1;
    // running XF store pointer (uniform bump instead of per-step recompute)
    unsigned short* xfp = XF + ((((size_t)t * 4 + kk1) * NTILE + gtile) * 64 + lp) * 8 + jo;
    const ptrdiff_t xstep = (ptrdiff_t)dt * 4 * NTILE * 64 * 8;

#define L1_STEP(RB, WB)                                                        \
    {                                                                          \
        float xt = x1s[t][wsh * 16 + col];                                     \
        f32x4 acc[4];                                                          \
        _Pragma("unroll") for (int g = 0; g < 4; ++g)                          \
            _Pragma("unroll") for (int r = 0; r < 4; ++r)                      \
                acc[g][r] = bvv[g][r] + wvv[g][r] * xt;                        \
        {                                                                      \
            s16x8 hb00 = *(const s16x8*)&Htf[RB][0][0][wsh][lane][0];          \
            s16x8 hb01 = *(const s16x8*)&Htf[RB][0][1][wsh][lane][0];          \
            s16x8 hb10 = *(const s16x8*)&Htf[RB][1][0][wsh][lane][0];          \
            s16x8 hb11 = *(const s16x8*)&Htf[RB][1][1][wsh][lane][0];          \
            __builtin_amdgcn_s_setprio(1);                                     \
            _Pragma("unroll") for (int g = 0; g < 4; ++g) {                    \
                f32x4 a = MFMA16(whhA[g][0], hb00, acc[g]);                    \
                a = MFMA16(whhA[g][1], hb01, a);                               \
                a = MFMA16(whhA[g][0], hb10, a);                               \
                a = MFMA16(whhA[g][1], hb11, a);                               \
                acc[g] = a;                                                    \
            }                                                                  \
            __builtin_amdgcn_s_setprio(0);                                     \
        }                                                                      \
        CELL_PACK(acc)                                                         \
        *(uint2*)&Htf[WB][0][kkw][wsh][lp][jo] = vhi;                          \
        *(uint2*)&Htf[WB][1][kkw][wsh][lp][jo] = vlo;                          \
        *(uint2*)xfp = vhi;                                                    \
        xfp += xstep;                                                          \
        bar_lgkm();                                                            \
        t += dt;                                                               \
    }

    for (int it = 0; it < T1 / 2; ++it) {
        L1_STEP(0, 1)
        L1_STEP(1, 0)
    }
#undef L1_STEP
}

// ---------------- layer-2 BiLSTM ----------------
// R2 changes: single-buffered X-frags w/ odd-step prefetch (-32 VGPR), bias
// f32x4 directly as MFMA C operand (-16 movs/even step), setprio around MFMA
// clusters, running atomic pointer.
__global__ __launch_bounds__(512, 4) void k_lstm2(
    const float* __restrict__ BS,
    const float* __restrict__ fc2w,
    const unsigned short* __restrict__ WA2HH,
    const unsigned short* __restrict__ WA2IH,
    const unsigned short* __restrict__ XF,
    float* __restrict__ part)
{
    __shared__ unsigned short wAl[16][4][64][8];        // 64 KB: dir slice of WA2IH
    __shared__ unsigned short Htf[2][2][2][2][64][8];   // 16 KB
    int tid  = threadIdx.x;
    int lane = tid & 63;
    int w    = __builtin_amdgcn_readfirstlane(tid >> 6);
    int wh   = w & 3, wsh = w >> 2;
    int quad = lane >> 4, col = lane & 15;
    int dir  = blockIdx.y, bblk = blockIdx.x;
    int gtile = bblk * 2 + wsh;

    {   // stage Wih A-fragments (our dir) into LDS
        const uint4* src = (const uint4*)(WA2IH + (size_t)dir * 32768);
        uint4* dst = (uint4*)&wAl[0][0][0][0];
        for (int i = tid; i < 4096; i += 512) dst[i] = src[i];
    }
    {   // zero Htf[0] (8192 B)
        uint4* z = (uint4*)&Htf[0][0][0][0][0][0];
        uint4 zz; zz.x = 0u; zz.y = 0u; zz.z = 0u; zz.w = 0u;
        z[tid] = zz;
    }
    float f2v[4];
#pragma unroll
    for (int r = 0; r < 4; ++r)
        f2v[r] = fc2w[dir * 64 + wh * 16 + quad * 4 + r];

    s16x8 whhA[4][2];
#pragma unroll
    for (int g = 0; g < 4; ++g)
#pragma unroll
        for (int kk = 0; kk < 2; ++kk)
            whhA[g][kk] = *(const s16x8*)(WA2HH +
                ((size_t)((dir * 16 + (g * 4 + wh)) * 2 + kk) * 64 + lane) * 8);

    // prescaled bias held as f32x4 so it can be the MFMA C operand directly
    f32x4 bC[4];
    {
        const float* bsrc = BS + dir * 256 + wh * 16 + quad * 4;
#pragma unroll
        for (int g = 0; g < 4; ++g) {
            float4 b4 = *(const float4*)(bsrc + g * 64);
            bC[g][0] = b4.x; bC[g][1] = b4.y; bC[g][2] = b4.z; bC[g][3] = b4.w;
        }
    }

    float c4[4];
#pragma unroll
    for (int r = 0; r < 4; ++r) c4[r] = 0.f;

    int lq  = 2 * (wh & 1) + (quad >> 1);
    int lp  = lq * 16 + col;
    int jo  = (quad & 1) * 4;
    int kkw = wh >> 1;

    // preload pair-0 X-frags (single buffer; refilled during odd steps)
    s16x8 xb[4];
    {
        int tp0 = dir ? (T1 - 1) : 0;
#pragma unroll
        for (int kk = 0; kk < 4; ++kk)
            xb[kk] = *(const s16x8*)(XF +
                (((size_t)(tp0 * 4 + kk) * NTILE + gtile) * 64 + lane) * 8);
    }
    f32x4 xacc[4];
    __syncthreads();

    int t2 = dir ? (T2 - 1) : 0;
    const int dt = dir ? -1 : 1;
    int tpn = dir ? (T1 - 2) : 1;       // next pair to prefetch

    // running atomic target pointer (only lanes <16 use it)
    float* pp = part + ((size_t)(dir * T2 + t2)) * BATCH + bblk * 32 + wsh * 16 + lane;
    const ptrdiff_t pstep = (ptrdiff_t)dt * BATCH;

#define L2_HIDCELL(RB, WB)                                                     \
    {                                                                          \
        s16x8 hb00 = *(const s16x8*)&Htf[RB][0][0][wsh][lane][0];              \
        s16x8 hb01 = *(const s16x8*)&Htf[RB][0][1][wsh][lane][0];              \
        s16x8 hb10 = *(const s16x8*)&Htf[RB][1][0][wsh][lane][0];              \
        s16x8 hb11 = *(const s16x8*)&Htf[RB][1][1][wsh][lane][0];              \
        f32x4 acc[4];                                                          \
        __builtin_amdgcn_s_setprio(1);                                         \
        _Pragma("unroll") for (int g = 0; g < 4; ++g) {                        \
            f32x4 a = MFMA16(whhA[g][0], hb00, xacc[g]);                       \
            a = MFMA16(whhA[g][1], hb01, a);                                   \
            a = MFMA16(whhA[g][0], hb10, a);                                   \
            a = MFMA16(whhA[g][1], hb11, a);                                   \
            acc[g] = a;                                                        \
        }                                                                      \
        __builtin_amdgcn_s_setprio(0);                                         \
        CELL_PACK(acc)                                                         \
        *(uint2*)&Htf[WB][0][kkw][wsh][lp][jo] = vhi;                          \
        *(uint2*)&Htf[WB][1][kkw][wsh][lp][jo] = vlo;                          \
        float pacc = f2v[0]*hv[0] + f2v[1]*hv[1] + f2v[2]*hv[2] + f2v[3]*hv[3];\
        pacc += __shfl_xor(pacc, 16);                                          \
        pacc += __shfl_xor(pacc, 32);                                          \
        if (lane < 16) atomicAdd(pp, pacc);                                    \
        pp += pstep;                                                           \
        bar_lgkm();                                                            \
        t2 += dt;                                                              \
    }

#define L2_EVEN()                                                              \
    {                                                                          \
        __builtin_amdgcn_s_setprio(1);                                         \
        _Pragma("unroll") for (int g = 0; g < 4; ++g) {                        \
            s16x8 wa0 = *(const s16x8*)&wAl[g * 4 + wh][0][lane][0];           \
            f32x4 a = MFMA16(wa0, xb[0], bC[g]);                               \
            _Pragma("unroll") for (int kk = 1; kk < 4; ++kk) {                 \
                s16x8 wa = *(const s16x8*)&wAl[g * 4 + wh][kk][lane][0];       \
                a = MFMA16(wa, xb[kk], a);                                     \
            }                                                                  \
            xacc[g] = a;                                                       \
        }                                                                      \
        __builtin_amdgcn_s_setprio(0);                                         \
    }

#define L2_PREF()                                                              \
    {                                                                          \
        _Pragma("unroll") for (int kk = 0; kk < 4; ++kk)                       \
            xb[kk] = *(const s16x8*)(XF +                                      \
                (((size_t)(tpn * 4 + kk) * NTILE + gtile) * 64 + lane) * 8);   \
        tpn += dt;                                                             \
        if (tpn < 0) tpn = 0;                                                  \
        if (tpn > T1 - 1) tpn = T1 - 1;                                        \
    }

    for (int it = 0; it < T2 / 4; ++it) {
        L2_EVEN()
        L2_HIDCELL(0, 1)
        L2_PREF()
        L2_HIDCELL(1, 0)
        L2_EVEN()
        L2_HIDCELL(0, 1)
        L2_PREF()
        L2_HIDCELL(1, 0)
    }
#undef L2_EVEN
#undef L2_PREF
#undef L2_HIDCELL
}

// ---------------- combine + tanh ----------------
__global__ __launch_bounds__(256) void k_fc2(const float* __restrict__ part,
                                             const float* __restrict__ fc2b,
                                             float* __restrict__ out) {
    int u = blockIdx.x * 256 + threadIdx.x;
    if (u >= BATCH * T2) return;
    int b = u / T2, t = u - b * T2;
    float p = part[(size_t)t * BATCH + b] + part[((size_t)T2 + t) * BATCH + b] + fc2b[0];
    out[u] = tanh_(p);
}

extern "C" void kernel_launch(void* const* d_in, const int* in_sizes, int n_in,
                              void* d_out, int out_size, void* d_ws, size_t ws_size,
                              hipStream_t stream) {
    const float* x      = (const float*)d_in[0];
    const float* fc1w   = (const float*)d_in[1];
    const float* fc1b   = (const float*)d_in[2];
    const float* r1wihf = (const float*)d_in[3];
    const float* r1whhf = (const float*)d_in[4];
    const float* r1bf   = (const float*)d_in[5];
    const float* r1wihb = (const float*)d_in[6];
    const float* r1whhb = (const float*)d_in[7];
    const float* r1bb   = (const float*)d_in[8];
    const float* r2wihf = (const float*)d_in[9];
    const float* r2whhf = (const float*)d_in[10];
    const float* r2bf   = (const float*)d_in[11];
    const float* r2wihb = (const float*)d_in[12];
    const float* r2whhb = (const float*)d_in[13];
    const float* r2bb   = (const float*)d_in[14];
    const float* fc2w   = (const float*)d_in[15];
    const float* fc2b   = (const float*)d_in[16];
    char* ws   = (char*)d_ws;
    float* out = (float*)d_out;

    float*          fc1T  = (float*)(ws + OFF_FC1T);
    unsigned short* XF    = (unsigned short*)(ws + OFF_XF);
    unsigned short* WA1   = (unsigned short*)(ws + OFF_WA1);
    unsigned short* WA2HH = (unsigned short*)(ws + OFF_WA2HH);
    unsigned short* WA2IH = (unsigned short*)(ws + OFF_WA2IH);
    float*          partp = (float*)(ws + OFF_PART);
    float*          BS    = (float*)(ws + OFF_BS);

    k_pre<<<353, 256, 0, stream>>>(r1whhf, r1whhb, r2whhf, r2whhb, r2wihf, r2wihb,
                                   r2bf, r2bb, x, fc1w, fc1b,
                                   WA1, WA2HH, WA2IH, fc1T, partp, BS);
    dim3 g1(NB2, 2);
    k_lstm1<<<g1, 512, 0, stream>>>(r1wihf, r1bf, r1wihb, r1bb, WA1, fc1T, XF);
    k_lstm2<<<g1, 512, 0, stream>>>(BS, fc2w, WA2HH, WA2IH, XF, partp);
    k_fc2<<<(BATCH * T2 + 255) / 256, 256, 0, stream>>>(partp, fc2b, out);
}